// Round 6
// baseline (281.789 us; speedup 1.0000x reference)
//
#include <hip/hip_runtime.h>

#define BB  8
#define NN1 1024
#define NN2 256
#define DD  16
#define EE  16
#define NCOL (NN2 * DD)   // 4096

using bf16x8  = __attribute__((ext_vector_type(8))) short;
using f32x4   = __attribute__((ext_vector_type(4))) float;

__device__ __forceinline__ ushort f2bf(float x) {
  unsigned u = __float_as_uint(x);
  unsigned r = (u + 0x7FFFu + ((u >> 16) & 1u)) >> 16;
  return (ushort)r;
}
__device__ __forceinline__ float bf2f(ushort u) {
  return __uint_as_float((unsigned)u << 16);
}
__device__ __forceinline__ unsigned pkbf(float a, float b) {
  return (unsigned)f2bf(a) | ((unsigned)f2bf(b) << 16);
}

#define GLDS16(g, l)                                                       \
  __builtin_amdgcn_global_load_lds(                                        \
      (const __attribute__((address_space(1))) void*)(g),                  \
      (__attribute__((address_space(3))) void*)(l), 16, 0, 0)

// ---------------------------------------------------------------------------
// k_prep: transpose + fp32->bf16 (+ optional 16B-chunk swizzle for LDS-staged
// consumers). src fp32 [kd(k)][nr], dst bf16 [nr][kd].
// ---------------------------------------------------------------------------
__global__ __launch_bounds__(256)
void k_prep(const float* __restrict__ src, ushort* __restrict__ dst,
            int nr, int kd, size_t srcBatch, size_t dstBatch, int swz) {
  __shared__ float tile[64][65];
  const int t = threadIdx.x;
  const int r0 = blockIdx.x * 64;
  const int k0 = blockIdx.y * 64;
  const float* s = src + (size_t)blockIdx.z * srcBatch;
  ushort* d = dst + (size_t)blockIdx.z * dstBatch;

#pragma unroll
  for (int it = 0; it < 4; ++it) {
    const int kr = it * 16 + (t >> 4);
    const int rc = (t & 15) * 4;
    float4 v = *reinterpret_cast<const float4*>(&s[(size_t)(k0 + kr) * nr + r0 + rc]);
    tile[kr][rc] = v.x; tile[kr][rc + 1] = v.y;
    tile[kr][rc + 2] = v.z; tile[kr][rc + 3] = v.w;
  }
  __syncthreads();

#pragma unroll
  for (int pass = 0; pass < 2; ++pass) {
    const int task = t + pass * 256;
    const int pr = task >> 3;
    const int gl = task & 7;
    const int r = r0 + pr;
    const int f = swz ? ((r >> 1) & 3) : 0;
    const int klb = (gl >> 2) * 32 + ((gl & 3) ^ f) * 8;
    unsigned w[4];
#pragma unroll
    for (int e2 = 0; e2 < 4; ++e2)
      w[e2] = pkbf(tile[klb + e2 * 2][pr], tile[klb + e2 * 2 + 1][pr]);
    *reinterpret_cast<uint4*>(&d[(size_t)r * kd + k0 + gl * 8]) =
        *reinterpret_cast<const uint4*>(w);
  }
}

// ---------------------------------------------------------------------------
// k_mode0_mfma: Y[b][p][c] = sum_k adj0[k][p] * X[b][k][c]  -> bf16
// 128x128 tile, BK=32, 2-phase pipeline: stage(t+1) issued before compute(t),
// counted vmcnt(4), raw s_barrier (no vmcnt(0) re-drain).
// ---------------------------------------------------------------------------
__global__ __launch_bounds__(256)
void k_mode0_mfma(const ushort* __restrict__ At, const ushort* __restrict__ Xt,
                  ushort* __restrict__ Y) {
  __shared__ ushort As[2][128 * 32];
  __shared__ ushort Bs[2][128 * 32];

  const int t = threadIdx.x;
  const int lane = t & 63;
  const int wid = t >> 6;
  const int wm = wid >> 1, wn = wid & 1;
  const int b  = blockIdx.x >> 5;
  const int c0 = (blockIdx.x & 31) << 7;
  const int p0 = blockIdx.y << 7;

  const ushort* Bb = Xt + (size_t)b * (NCOL * 1024);

  f32x4 acc[4][4];
#pragma unroll
  for (int i = 0; i < 4; ++i)
#pragma unroll
    for (int j = 0; j < 4; ++j) acc[i][j] = (f32x4)0.f;

  const int srow = wid * 32 + (lane >> 2);
  const int schk = (lane & 3) * 8;
  const size_t aoff0 = (size_t)(p0 + srow) * 1024 + schk;
  const size_t boff0 = (size_t)(c0 + srow) * 1024 + schk;
  const int lw0 = (wid * 32) * 32;
  const int lw1 = (wid * 32 + 16) * 32;

  const int lm = lane & 15, g = lane >> 4;
  int aro[4], bro[4];
#pragma unroll
  for (int f = 0; f < 4; ++f) {
    const int ra = wm * 64 + f * 16 + lm;
    aro[f] = ra * 32 + ((g ^ ((ra >> 1) & 3)) << 3);
    const int rb = wn * 64 + f * 16 + lm;
    bro[f] = rb * 32 + ((g ^ ((rb >> 1) & 3)) << 3);
  }

#define STAGE(buf, kk)                                                     \
  do {                                                                     \
    GLDS16(At + aoff0 + (kk), &As[buf][lw0]);                              \
    GLDS16(At + aoff0 + 16 * 1024 + (kk), &As[buf][lw1]);                  \
    GLDS16(Bb + boff0 + (kk), &Bs[buf][lw0]);                              \
    GLDS16(Bb + boff0 + 16 * 1024 + (kk), &Bs[buf][lw1]);                  \
  } while (0)

  STAGE(0, 0);
  int cur = 0;

  for (int k0 = 0; k0 < 1024; k0 += 32) {
    if (k0 + 32 < 1024) {
      STAGE(cur ^ 1, k0 + 32);
      asm volatile("s_waitcnt vmcnt(4)" ::: "memory");
    } else {
      asm volatile("s_waitcnt vmcnt(0)" ::: "memory");
    }
    __builtin_amdgcn_s_barrier();
    __builtin_amdgcn_sched_barrier(0);

    bf16x8 af[4], bfr[4];
#pragma unroll
    for (int f = 0; f < 4; ++f)
      af[f] = *reinterpret_cast<const bf16x8*>(&As[cur][aro[f]]);
#pragma unroll
    for (int f = 0; f < 4; ++f)
      bfr[f] = *reinterpret_cast<const bf16x8*>(&Bs[cur][bro[f]]);

#pragma unroll
    for (int i = 0; i < 4; ++i)
#pragma unroll
      for (int j = 0; j < 4; ++j)
        acc[i][j] = __builtin_amdgcn_mfma_f32_16x16x32_bf16(af[i], bfr[j], acc[i][j], 0, 0, 0);

    __builtin_amdgcn_sched_barrier(0);
    __builtin_amdgcn_s_barrier();
    cur ^= 1;
  }
#undef STAGE

  ushort* Yb = Y + (size_t)b * (NN1 * NCOL);
  const int orow = (lane >> 4) * 4;
  const int ocol = lane & 15;
#pragma unroll
  for (int i = 0; i < 4; ++i)
#pragma unroll
    for (int j = 0; j < 4; ++j) {
      const int p = p0 + wm * 64 + i * 16 + orow;
      const int c = c0 + wn * 64 + j * 16 + ocol;
      ushort* dst = Yb + (size_t)p * NCOL + c;
#pragma unroll
      for (int e = 0; e < 4; ++e) dst[(size_t)e * NCOL] = f2bf(acc[i][j][e]);
    }
}

// ---------------------------------------------------------------------------
// k_pm1: one block per (b,p) slice. Fused proj + mode1:
//   xy LDS row j = [x(j,0..15)|y0(j,0..15)] bf16
//   r-acc = mfma(xy, [W;W_s0], bias)          (K=32, D rows=j, cols=e)
//   s     = mfma(xy, [W_s1;W_s01], 0) -> LDS [e][j] bf16
//   acc  += sum_ks mfma(A1t_frag(global), s_frag, .)   (K=256)
//   out   = relu(acc)
// ---------------------------------------------------------------------------
#define XYP 40    // xy row pitch (ushorts): 80B -> 2-way banks
#define SMP 264   // s row pitch  (ushorts): 528B -> 2-way banks

__global__ __launch_bounds__(256)
void k_pm1(const float* __restrict__ x, const ushort* __restrict__ y0,
           const ushort* __restrict__ A1t,
           const float* __restrict__ W,   const float* __restrict__ bW,
           const float* __restrict__ W0,  const float* __restrict__ b0,
           const float* __restrict__ W1,  const float* __restrict__ b1,
           const float* __restrict__ W01, const float* __restrict__ b01,
           float* __restrict__ out) {
  __shared__ ushort xy[256 * XYP];
  __shared__ ushort sm[16 * SMP];

  const int t = threadIdx.x;
  const int lane = t & 63;
  const int wid = t >> 6;
  const int e  = lane & 15;
  const int kg = lane >> 4;          // 0..3; k-base = kg*8 (frag), q-sub = kg*4 (D)

  const size_t slice = blockIdx.x;
  const float*  xs = x  + slice * NCOL;
  const ushort* ys = y0 + slice * NCOL;

  // --- stage xy: thread t owns row j=t ---
  {
    ushort* row = xy + t * XYP;
    const float4 x0 = *reinterpret_cast<const float4*>(xs + t * 16);
    const float4 x1 = *reinterpret_cast<const float4*>(xs + t * 16 + 4);
    const float4 x2 = *reinterpret_cast<const float4*>(xs + t * 16 + 8);
    const float4 x3 = *reinterpret_cast<const float4*>(xs + t * 16 + 12);
    unsigned w0[4] = {pkbf(x0.x, x0.y), pkbf(x0.z, x0.w), pkbf(x1.x, x1.y), pkbf(x1.z, x1.w)};
    unsigned w1[4] = {pkbf(x2.x, x2.y), pkbf(x2.z, x2.w), pkbf(x3.x, x3.y), pkbf(x3.z, x3.w)};
    *reinterpret_cast<uint4*>(row)      = *reinterpret_cast<const uint4*>(w0);
    *reinterpret_cast<uint4*>(row + 8)  = *reinterpret_cast<const uint4*>(w1);
    *reinterpret_cast<uint4*>(row + 16) = *reinterpret_cast<const uint4*>(ys + t * 16);
    *reinterpret_cast<uint4*>(row + 24) = *reinterpret_cast<const uint4*>(ys + t * 16 + 8);
  }

  // --- W fragments (lane: "row"=e, k=kg*8+jj over [d_x(16)|d_y(16)]) ---
  bf16x8 wfr, wfs;
#pragma unroll
  for (int jj = 0; jj < 8; ++jj) {
    const int k = kg * 8 + jj;
    const float vr = (k < 16) ? W[k * 16 + e]  : W0[(k - 16) * 16 + e];
    const float vs = (k < 16) ? W1[k * 16 + e] : W01[(k - 16) * 16 + e];
    wfr[jj] = (short)f2bf(vr);
    wfs[jj] = (short)f2bf(vs);
  }
  const float bias = bW[e] + b0[e] + b1[e] + b01[e];

  __syncthreads();

  // --- proj MFMAs: wave handles j-groups g = wid*4..wid*4+3 ---
  f32x4 acc[4];
#pragma unroll
  for (int gi = 0; gi < 4; ++gi) {
    const int gq = wid * 4 + gi;
    const bf16x8 a = *reinterpret_cast<const bf16x8*>(
        xy + (gq * 16 + e) * XYP + kg * 8);
    f32x4 cb; cb[0] = bias; cb[1] = bias; cb[2] = bias; cb[3] = bias;
    acc[gi] = __builtin_amdgcn_mfma_f32_16x16x32_bf16(a, wfr, cb, 0, 0, 0);
    f32x4 sD = __builtin_amdgcn_mfma_f32_16x16x32_bf16(a, wfs, (f32x4)0.f, 0, 0, 0);
    // D: col=e, rows j = gq*16 + kg*4 + r  -> sm[e][j]
    ushort* srow = sm + e * SMP + gq * 16 + kg * 4;
    *reinterpret_cast<unsigned*>(srow)     = pkbf(sD[0], sD[1]);
    *reinterpret_cast<unsigned*>(srow + 2) = pkbf(sD[2], sD[3]);
  }

  __syncthreads();

  // --- mode1: acc += sum_j adj1[j][q] * s[j][e] via MFMA, K=256 ---
#pragma unroll
  for (int gi = 0; gi < 4; ++gi) {
    const int gq = wid * 4 + gi;
    const ushort* arow = A1t + (size_t)(gq * 16 + e) * 256 + kg * 8;
#pragma unroll
    for (int ks = 0; ks < 8; ++ks) {
      const bf16x8 a1 = *reinterpret_cast<const bf16x8*>(arow + ks * 32);
      const bf16x8 sf = *reinterpret_cast<const bf16x8*>(sm + e * SMP + ks * 32 + kg * 8);
      acc[gi] = __builtin_amdgcn_mfma_f32_16x16x32_bf16(a1, sf, acc[gi], 0, 0, 0);
    }
  }

  // --- store: out[slice][q][e] = relu(acc), q = gq*16 + kg*4 + r ---
  float* os = out + slice * NCOL;
#pragma unroll
  for (int gi = 0; gi < 4; ++gi) {
    const int q0 = (wid * 4 + gi) * 16 + kg * 4;
#pragma unroll
    for (int r = 0; r < 4; ++r)
      os[(q0 + r) * 16 + e] = fmaxf(acc[gi][r], 0.f);
  }
}

// ---------------------------------------------------------------------------
extern "C" void kernel_launch(void* const* d_in, const int* in_sizes, int n_in,
                              void* d_out, int out_size, void* d_ws, size_t ws_size,
                              hipStream_t stream) {
  const float* x    = (const float*)d_in[0];
  const float* adj0 = (const float*)d_in[1];
  const float* adj1 = (const float*)d_in[2];
  const float* W    = (const float*)d_in[3];
  const float* bW   = (const float*)d_in[4];
  const float* Ws0  = (const float*)d_in[5];
  const float* bs0  = (const float*)d_in[6];
  const float* Ws1  = (const float*)d_in[7];
  const float* bs1  = (const float*)d_in[8];
  const float* Ws01 = (const float*)d_in[9];
  const float* bs01 = (const float*)d_in[10];
  float* out = (float*)d_out;

  const size_t SLICE = (size_t)NN1 * NCOL;
  const size_t AT_B  = (size_t)1024 * 1024 * 2;       // adj0^T bf16 (swizzled)
  const size_t A1T_B = (size_t)256 * 256 * 2;         // adj1^T bf16 (linear)
  const size_t XT_B  = (size_t)NCOL * 1024 * 2;       // per-batch, 8.4 MB
  const size_t Y0_B  = SLICE * 2;                     // per-batch bf16, 8.4 MB
  const size_t HEAD  = AT_B + A1T_B;
  const size_t PER_B = XT_B + Y0_B;

  int nb_max = (int)((ws_size > HEAD ? ws_size - HEAD : 0) / PER_B);
  if (nb_max > BB) nb_max = BB;
  if (nb_max < 1)  nb_max = 1;

  ushort* At  = (ushort*)d_ws;
  ushort* A1t = (ushort*)((char*)d_ws + AT_B);
  ushort* Xt  = (ushort*)((char*)d_ws + HEAD);
  ushort* y0  = (ushort*)((char*)d_ws + HEAD + (size_t)nb_max * XT_B);

  k_prep<<<dim3(16, 16, 1), 256, 0, stream>>>(adj0, At, 1024, 1024, 0, 0, 1);
  k_prep<<<dim3(4, 4, 1), 256, 0, stream>>>(adj1, A1t, 256, 256, 0, 0, 0);

  for (int c0 = 0; c0 < BB; c0 += nb_max) {
    const int nb = (BB - c0 < nb_max) ? (BB - c0) : nb_max;
    const float* xc = x   + (size_t)c0 * SLICE;
    float*       oc = out + (size_t)c0 * SLICE;

    k_prep<<<dim3(NCOL / 64, 16, nb), 256, 0, stream>>>(
        xc, Xt, NCOL, 1024, SLICE, (size_t)NCOL * 1024, 1);

    dim3 g1(nb * 32, 8);
    k_mode0_mfma<<<g1, 256, 0, stream>>>(At, Xt, y0);

    k_pm1<<<dim3(nb * NN1), 256, 0, stream>>>(xc, y0, A1t, W, bW, Ws0, bs0,
                                              Ws1, bs1, Ws01, bs01, oc);
  }
}